// Round 8
// baseline (242.627 us; speedup 1.0000x reference)
//
#include <hip/hip_runtime.h>
#include <hip/hip_bf16.h>
#include <math.h>
#include <stdint.h>

typedef __bf16 bf16;
typedef __bf16 bf16x8 __attribute__((ext_vector_type(8)));
typedef __bf16 bf16x4v __attribute__((ext_vector_type(4)));
typedef float f32x4 __attribute__((ext_vector_type(4)));

#define NHEADS 4
#define DM 768
#define DB 64
#define HD 192
#define BATCH 8
#define SEQ 1024
#define MROWS 8192
#define SCALE 0.07216878364870323f

__device__ __forceinline__ void gld_lds16(const void* g, void* l) {
  __builtin_amdgcn_global_load_lds(
      (__attribute__((address_space(1))) void*)(void*)g,
      (__attribute__((address_space(3))) void*)l, 16, 0, 0);
}

// ---------------- converts ----------------
__global__ __launch_bounds__(256) void cvt_f32_bf16(const float* __restrict__ in,
                                                    bf16* __restrict__ out, long n4) {
  long i = (long)blockIdx.x * blockDim.x + threadIdx.x;
  if (i >= n4) return;
  f32x4 v = *(const f32x4*)&in[i * 4];
  bf16x4v t;
  t[0] = (bf16)v[0]; t[1] = (bf16)v[1]; t[2] = (bf16)v[2]; t[3] = (bf16)v[3];
  *(bf16x4v*)&out[i * 4] = t;
}

__global__ __launch_bounds__(256) void transpose_bf16(const float* __restrict__ W,
                                                      bf16* __restrict__ WT, int K, int N) {
  long idx = (long)blockIdx.x * blockDim.x + threadIdx.x;
  if (idx >= (long)K * N) return;
  int k = (int)(idx % K);
  int n = (int)(idx / K);
  WT[(long)n * K + k] = (bf16)W[(long)k * N + n];
}

// ---------------- bias MLP ----------------
__global__ __launch_bounds__(256) void bias_mlp(const float* __restrict__ bloom,
                                                const float* __restrict__ Wb1,
                                                const float* __restrict__ bb1,
                                                const float* __restrict__ Wb2,
                                                const float* __restrict__ bb2,
                                                float* __restrict__ biasarr) {
  int idx = blockIdx.x * blockDim.x + threadIdx.x;
  if (idx >= MROWS) return;
  const float* x = bloom + (long)idx * DB;
  float h[8];
#pragma unroll
  for (int j = 0; j < 8; ++j) h[j] = bb1[j];
  for (int k = 0; k < DB; ++k) {
    float xv = x[k];
#pragma unroll
    for (int j = 0; j < 8; ++j) h[j] = fmaf(xv, Wb1[k * 8 + j], h[j]);
  }
#pragma unroll
  for (int j = 0; j < 8; ++j) {
    float a = h[j];
    h[j] = 0.5f * a * (1.0f + erff(a * 0.7071067811865476f));
  }
  int b = idx >> 10, s = idx & 1023;
#pragma unroll
  for (int o = 0; o < 4; ++o) {
    float a = bb2[o];
#pragma unroll
    for (int j = 0; j < 8; ++j) a = fmaf(h[j], Wb2[j * 4 + o], a);
    biasarr[((long)(b * 4 + o) << 10) + s] = a;
  }
}

// ---------------- row-sum + normalize (streaming, full occupancy) ----------------
// 8192 blocks x 256 thr: one wave per row of 1024. E bf16 (L3-hot) -> attn f32 + inv.
__global__ __launch_bounds__(256) void rowsum_scale_bf16(const bf16* __restrict__ E,
                                                         float* __restrict__ attn,
                                                         float* __restrict__ inv) {
  const int row = blockIdx.x * 4 + (threadIdx.x >> 6);
  const int lane = threadIdx.x & 63;
  const bf16* er = E + ((long)row << 10);
  float* ar = attn + ((long)row << 10);
  bf16x8 v0 = *(const bf16x8*)&er[lane * 8];
  bf16x8 v1 = *(const bf16x8*)&er[512 + lane * 8];
  float f[16];
  float s = 0.0f;
#pragma unroll
  for (int e = 0; e < 8; ++e) { f[e] = (float)v0[e]; f[8 + e] = (float)v1[e]; }
#pragma unroll
  for (int e = 0; e < 16; ++e) s += f[e];
  for (int d = 1; d < 64; d <<= 1) s += __shfl_xor(s, d);
  float iv = 1.0f / s;
  if (lane == 0) inv[row] = iv;
  f32x4 w;
  w[0] = f[0] * iv; w[1] = f[1] * iv; w[2] = f[2] * iv; w[3] = f[3] * iv;
  *(f32x4*)&ar[lane * 8] = w;
  w[0] = f[4] * iv; w[1] = f[5] * iv; w[2] = f[6] * iv; w[3] = f[7] * iv;
  *(f32x4*)&ar[lane * 8 + 4] = w;
  w[0] = f[8] * iv; w[1] = f[9] * iv; w[2] = f[10] * iv; w[3] = f[11] * iv;
  *(f32x4*)&ar[512 + lane * 8] = w;
  w[0] = f[12] * iv; w[1] = f[13] * iv; w[2] = f[14] * iv; w[3] = f[15] * iv;
  *(f32x4*)&ar[512 + lane * 8 + 4] = w;
}

// fallback: E was written f32 into attn; normalize in place.
__global__ __launch_bounds__(256) void rowsum_scale_f32(float* __restrict__ attn) {
  const int row = blockIdx.x * 4 + (threadIdx.x >> 6);
  const int lane = threadIdx.x & 63;
  float* ar = attn + ((long)row << 10);
  f32x4 v[4];
#pragma unroll
  for (int i = 0; i < 4; ++i) v[i] = *(const f32x4*)&ar[i * 256 + lane * 4];
  float s = 0.0f;
#pragma unroll
  for (int i = 0; i < 4; ++i)
#pragma unroll
    for (int j = 0; j < 4; ++j) s += v[i][j];
  for (int d = 1; d < 64; d <<= 1) s += __shfl_xor(s, d);
  float iv = 1.0f / s;
#pragma unroll
  for (int i = 0; i < 4; ++i) {
#pragma unroll
    for (int j = 0; j < 4; ++j) v[i][j] *= iv;
    *(f32x4*)&ar[i * 256 + lane * 4] = v[i];
  }
}

// ---------------- GEMM (A row-major [M,K] bf16, BT row-major [N,K] bf16) ----------------
// MODE 0: bf16 out natural +cb1                         (K projection)
// MODE 2: E = exp(v*SCALE + bias) bf16, batched          (scores, 2048 blocks)
// MODE 7: like 2 but f32 out into attn                   (fallback)
// MODE 3: A bf16 batched (E), out bf16 ctx * inv[row]    (PV fast, 512 blocks)
// MODE 5: A f32 batched (normalized attn), out bf16 ctx  (PV fallback)
// MODE 4: f32 out = acc + cb1 + resid                    (final x)
// MODE 6: fused QV: ng<768 -> Q natural (+cb1); else V scatter-transposed (+cb2)
template <int MODE>
__global__ __launch_bounds__(256) void gemm_bt(
    const bf16* __restrict__ A, int lda,
    const bf16* __restrict__ BT, int ldb,
    const float* __restrict__ Af,
    int M, int N, int Kd,
    const float* __restrict__ cb1,
    const float* __restrict__ cb2,
    const float* __restrict__ resid,
    void* __restrict__ out, void* __restrict__ out2) {
  __shared__ __attribute__((aligned(16))) bf16 aL[128 * 32];
  __shared__ __attribute__((aligned(16))) bf16 bL[128 * 32];
  const int tid = threadIdx.x;
  const int lane = tid & 63;
  const int wid = tid >> 6;
  const int wr = wid >> 1, wc = wid & 1;
  int bx, by, bz;
  if constexpr (MODE == 2 || MODE == 7) {
    int idd = blockIdx.x;
    bz = idd & 31;
    int t = idd >> 5;
    bx = t & 7;
    by = t >> 3;
  } else if constexpr (MODE == 3 || MODE == 5) {
    int idd = blockIdx.x;
    bz = idd & 31;
    bx = (idd >> 5) & 1;
    by = idd >> 6;
  } else {
    bx = blockIdx.x; by = blockIdx.y; bz = 0;
  }
  const int m0 = by * 128, n0 = bx * 128;

  const bf16* Ab = A;
  const bf16* Bb = BT;
  if constexpr (MODE == 2 || MODE == 7) {
    long o = ((long)((bz >> 2) * SEQ)) * DM + (long)(bz & 3) * HD;
    Ab = A + o;
    Bb = BT + o;
  }
  if constexpr (MODE == 3) {
    Ab = A + ((long)bz << 20);
    Bb = BT + (((long)((bz >> 2) * DM + (bz & 3) * HD)) << 10);
  }
  if constexpr (MODE == 5) {
    Bb = BT + (((long)((bz >> 2) * DM + (bz & 3) * HD)) << 10);
  }
  const float* Afb = (MODE == 5) ? (Af + ((long)bz << 20)) : nullptr;

  f32x4 acc[4][4] = {};

  for (int k0 = 0; k0 < Kd; k0 += 32) {
    if constexpr (MODE == 5) {
#pragma unroll
      for (int p = 0; p < 2; ++p) {
        int f = (p * 256 + tid) * 8;
        int row = f >> 5, col = f & 31;
        const float* g = Afb + (long)(m0 + row) * lda + k0 + col;
        f32x4 x0 = *(const f32x4*)g;
        f32x4 x1 = *(const f32x4*)(g + 4);
        bf16x8 t;
        t[0] = (bf16)x0[0]; t[1] = (bf16)x0[1]; t[2] = (bf16)x0[2]; t[3] = (bf16)x0[3];
        t[4] = (bf16)x1[0]; t[5] = (bf16)x1[1]; t[6] = (bf16)x1[2]; t[7] = (bf16)x1[3];
        *(bf16x8*)&aL[f] = t;
      }
    } else {
#pragma unroll
      for (int p = 0; p < 2; ++p) {
        int f = (p * 256 + tid) * 8;
        int row = f >> 5, col = f & 31;
        gld_lds16(Ab + (long)(m0 + row) * lda + k0 + col, &aL[f]);
      }
    }
#pragma unroll
    for (int p = 0; p < 2; ++p) {
      int f = (p * 256 + tid) * 8;
      int row = f >> 5, col = f & 31;
      int nn = n0 + row;
      nn = nn < N ? nn : N - 1;
      gld_lds16(Bb + (long)nn * ldb + k0 + col, &bL[f]);
    }
    __syncthreads();

    const int rsel = lane & 15, ksel = (lane >> 4) * 8;
    bf16x8 af[4], bfr[4];
#pragma unroll
    for (int m = 0; m < 4; ++m)
      af[m] = *(const bf16x8*)&aL[(wr * 64 + m * 16 + rsel) * 32 + ksel];
#pragma unroll
    for (int n = 0; n < 4; ++n)
      bfr[n] = *(const bf16x8*)&bL[(wc * 64 + n * 16 + rsel) * 32 + ksel];
#pragma unroll
    for (int m = 0; m < 4; ++m)
#pragma unroll
      for (int n = 0; n < 4; ++n)
        acc[m][n] = __builtin_amdgcn_mfma_f32_16x16x32_bf16(af[m], bfr[n], acc[m][n], 0, 0, 0);
    __syncthreads();
  }

  const int rl = (lane >> 4) * 4, cl = lane & 15;
#pragma unroll
  for (int m = 0; m < 4; ++m) {
#pragma unroll
    for (int n = 0; n < 4; ++n) {
      int ng = n0 + wc * 64 + n * 16 + cl;
      if (ng >= N) continue;
#pragma unroll
      for (int j = 0; j < 4; ++j) {
        int mg = m0 + wr * 64 + m * 16 + rl + j;
        float v = acc[m][n][j];
        if constexpr (MODE == 0) {
          ((bf16*)out)[(long)mg * DM + ng] = (bf16)(v + cb1[ng]);
        } else if constexpr (MODE == 2) {
          ((bf16*)out)[((long)bz << 20) + ((long)mg << 10) + ng] =
              (bf16)__expf(fmaf(v, SCALE, cb2[(bz << 10) + ng]));
        } else if constexpr (MODE == 7) {
          ((float*)out)[((long)bz << 20) + ((long)mg << 10) + ng] =
              __expf(fmaf(v, SCALE, cb2[(bz << 10) + ng]));
        } else if constexpr (MODE == 3) {
          ((bf16*)out)[(long)((bz >> 2) * SEQ + mg) * DM + (bz & 3) * HD + ng] =
              (bf16)(v * cb2[(bz << 10) + mg]);
        } else if constexpr (MODE == 5) {
          ((bf16*)out)[(long)((bz >> 2) * SEQ + mg) * DM + (bz & 3) * HD + ng] = (bf16)v;
        } else if constexpr (MODE == 6) {
          if (ng < DM) {
            ((bf16*)out)[(long)mg * DM + ng] = (bf16)(v + cb1[ng]);
          } else {
            int d = ng - DM;
            int b = mg >> 10, s = mg & 1023;
            ((bf16*)out2)[((long)(b * DM + d) << 10) + s] = (bf16)(v + cb2[d]);
          }
        } else {
          long o = (long)mg * DM + ng;
          ((float*)out)[o] = v + cb1[ng] + resid[o];
        }
      }
    }
  }
}

// ---------------- layernorm (one wave per row of 768, in place) ----------------
__global__ __launch_bounds__(256) void layernorm_rows(float* x, const float* __restrict__ gam,
                                                      const float* __restrict__ bet) {
  int row = blockIdx.x * 4 + (threadIdx.x >> 6);
  int lane = threadIdx.x & 63;
  float* r = x + (long)row * DM;
  f32x4 v[3];
#pragma unroll
  for (int i = 0; i < 3; ++i) v[i] = *(const f32x4*)&r[i * 256 + lane * 4];
  float s = 0.0f, ss = 0.0f;
#pragma unroll
  for (int i = 0; i < 3; ++i)
#pragma unroll
    for (int j = 0; j < 4; ++j) {
      s += v[i][j];
      ss += v[i][j] * v[i][j];
    }
  for (int d = 1; d < 64; d <<= 1) {
    s += __shfl_xor(s, d);
    ss += __shfl_xor(ss, d);
  }
  float mu = s * (1.0f / 768.0f);
  float var = ss * (1.0f / 768.0f) - mu * mu;
  float rs = 1.0f / sqrtf(var + 1e-5f);
#pragma unroll
  for (int i = 0; i < 3; ++i) {
#pragma unroll
    for (int j = 0; j < 4; ++j) {
      int c = i * 256 + lane * 4 + j;
      v[i][j] = (v[i][j] - mu) * rs * gam[c] + bet[c];
    }
    *(f32x4*)&r[i * 256 + lane * 4] = v[i];
  }
}

// ---------------- launcher ----------------
extern "C" void kernel_launch(void* const* d_in, const int* in_sizes, int n_in,
                              void* d_out, int out_size, void* d_ws, size_t ws_size,
                              hipStream_t stream) {
  const float* Xd = (const float*)d_in[0];
  const float* Xb = (const float*)d_in[1];
  const float* Wq = (const float*)d_in[2];
  const float* bq = (const float*)d_in[3];
  const float* Wk = (const float*)d_in[4];
  const float* bk = (const float*)d_in[5];
  const float* Wv = (const float*)d_in[6];
  const float* bv = (const float*)d_in[7];
  const float* Wb1 = (const float*)d_in[8];
  const float* bb1 = (const float*)d_in[9];
  const float* Wb2 = (const float*)d_in[10];
  const float* bb2 = (const float*)d_in[11];
  const float* Wo = (const float*)d_in[12];
  const float* bo = (const float*)d_in[13];
  const float* lng = (const float*)d_in[14];
  const float* lnb = (const float*)d_in[15];

  float* y = (float*)d_out;                  // 8192*768 f32
  float* attn = y + (long)MROWS * DM;        // 32*1024*1024 f32

  char* w = (char*)d_ws;
  bf16* Xd_bf = (bf16*)w; w += (long)MROWS * DM * 2;   // later reused as ctx
  bf16* Xb_bf = (bf16*)w; w += (long)MROWS * DB * 2;
  bf16* WqvT = (bf16*)w; w += (long)2 * DM * DM * 2;   // [1536][768]
  bf16* WkT = (bf16*)w; w += (long)DM * DB * 2;
  bf16* WoT = (bf16*)w; w += (long)DM * DM * 2;
  bf16* Qb = (bf16*)w; w += (long)MROWS * DM * 2;
  bf16* Kb = (bf16*)w; w += (long)MROWS * DM * 2;
  bf16* VTb = (bf16*)w; w += (long)MROWS * DM * 2;
  float* biasarr = (float*)w; w += (long)BATCH * NHEADS * SEQ * 4;
  float* inv = (float*)w; w += (long)32 * SEQ * 4;
  bf16* Sb = (bf16*)w; w += (long)32 * SEQ * SEQ * 2;  // 64 MB E buffer
  const bool useS = ((size_t)(w - (char*)d_ws)) <= ws_size;
  bf16* ctxb = Xd_bf;  // Xd_bf dead after QV projection; reuse for ctx

  cvt_f32_bf16<<<6144, 256, 0, stream>>>(Xd, Xd_bf, (long)MROWS * DM / 4);
  cvt_f32_bf16<<<512, 256, 0, stream>>>(Xb, Xb_bf, (long)MROWS * DB / 4);
  transpose_bf16<<<2304, 256, 0, stream>>>(Wq, WqvT, DM, DM);
  transpose_bf16<<<2304, 256, 0, stream>>>(Wv, WqvT + (long)DM * DM, DM, DM);
  transpose_bf16<<<192, 256, 0, stream>>>(Wk, WkT, DB, DM);
  transpose_bf16<<<2304, 256, 0, stream>>>(Wo, WoT, DM, DM);
  bias_mlp<<<32, 256, 0, stream>>>(Xb, Wb1, bb1, Wb2, bb2, biasarr);

  dim3 blk(256);
  // K = Xb @ Wk + bk
  gemm_bt<0><<<dim3(6, 64, 1), blk, 0, stream>>>(Xb_bf, DB, WkT, DB, nullptr, MROWS, DM, DB,
                                                 bk, nullptr, nullptr, Kb, nullptr);
  // [Q | V] = Xd @ [Wq | Wv]: Q natural -> Qb, V scatter-transposed -> VTb
  gemm_bt<6><<<dim3(12, 64, 1), blk, 0, stream>>>(Xd_bf, DM, WqvT, DM, nullptr, MROWS, 2 * DM, DM,
                                                  bq, bv, nullptr, Qb, VTb);
  if (useS) {
    // E = exp(QK^T*scale + bias) bf16, 2048 blocks
    gemm_bt<2><<<2048, blk, 0, stream>>>(Qb, DM, Kb, DM, nullptr, SEQ, SEQ, HD,
                                         nullptr, biasarr, nullptr, Sb, nullptr);
    // row sums -> attn f32 (+inv), full-occupancy streaming
    rowsum_scale_bf16<<<8192, blk, 0, stream>>>(Sb, attn, inv);
    // ctx = (E @ V) * inv
    gemm_bt<3><<<512, blk, 0, stream>>>(Sb, SEQ, VTb, SEQ, nullptr, SEQ, HD, SEQ,
                                        nullptr, inv, nullptr, ctxb, nullptr);
  } else {
    gemm_bt<7><<<2048, blk, 0, stream>>>(Qb, DM, Kb, DM, nullptr, SEQ, SEQ, HD,
                                         nullptr, biasarr, nullptr, attn, nullptr);
    rowsum_scale_f32<<<8192, blk, 0, stream>>>(attn);
    gemm_bt<5><<<512, blk, 0, stream>>>(nullptr, SEQ, VTb, SEQ, attn, SEQ, HD, SEQ,
                                        nullptr, nullptr, nullptr, ctxb, nullptr);
  }
  // x = ctx @ Wo + bo + resid -> y region, then LN in place
  gemm_bt<4><<<dim3(6, 64, 1), blk, 0, stream>>>(ctxb, DM, WoT, DM, nullptr, MROWS, DM, DM,
                                                 bo, nullptr, Xd, y, nullptr);
  layernorm_rows<<<2048, 256, 0, stream>>>(y, lng, lnb);
}